// Round 3
// baseline (1351.477 us; speedup 1.0000x reference)
//
#include <hip/hip_runtime.h>
#include <hip/hip_bf16.h>

#define BATCH 100000
#define SEQ   28
#define NIN   28
#define HID   64
#define NOUT  10
#define BM    64
#define NBLK  ((BATCH + BM - 1) / BM)
#define LOG2E 1.4426950408889634f

typedef short bf8 __attribute__((ext_vector_type(8)));   // 8 bf16 (4 VGPRs)
typedef short bf4 __attribute__((ext_vector_type(4)));
typedef float f4  __attribute__((ext_vector_type(4)));

__device__ __forceinline__ short f2bf(float f) {
    __hip_bfloat16 b = __float2bfloat16(f);   // RNE
    return *reinterpret_cast<short*>(&b);
}

// ---------------------------------------------------------------------------
// GRU v5: x prefetched to REGISTERS in 2-step chunks (no LDS x-stage).
// LDS = weights + h only (47.4 KB) -> 3 blocks/CU, ~3 waves/SIMD for TLP.
// Per block: 64 batch rows, 4 waves, wave w owns rows 16w..16w+15.
// gates[16x192] = x_t[16x32pad] @ Wih'^T + h[16x64] @ Whh'^T (+bias'); r,z
// weight rows pre-scaled by -log2e and n rows by 2*log2e so
// sigmoid(x)=rcp(1+exp2(u)) and tanh(y)=1-2*rcp(1+exp2(y')) need no in-loop
// scaling. No __syncthreads in the step loop: all data deps are wave-local.
// Wave-wide, each 2-step chunk reads 16 rows x 224 B contiguous (single-touch;
// adjacent-chunk line straddles hit L2 at 2-step reuse distance).
// ---------------------------------------------------------------------------
__global__ __launch_bounds__(256, 2) void gru_mfma5_kernel(
    const float* __restrict__ X,     // [B, S, 28]
    const float* __restrict__ Wih,   // [192, 28]
    const float* __restrict__ Whh,   // [192, 64]
    const float* __restrict__ bih,   // [192]
    const float* __restrict__ bhh,   // [192]
    const float* __restrict__ Wout,  // [10, 64]
    const float* __restrict__ bout,  // [10]
    float* __restrict__ out)         // [B, 10]
{
    __shared__ short sBih[12 * 64 * 8];        // 12 KB
    __shared__ short sBhh[12 * 2 * 64 * 8];    // 24 KB
    __shared__ short sBout[2 * 64 * 8];        // 2 KB
    __shared__ short sH[BM][66];               // 8.25 KB, padded stride

    const int tid = threadIdx.x;

    // ---- one-time: fp32 weights -> pre-scaled bf16 B-fragments in LDS ----
    for (int idx = tid; idx < 12 * 64; idx += 256) {
        int c = idx >> 6, ln = idx & 63;
        int g = 16 * c + (ln & 15), k0 = (ln >> 4) * 8;
        float sc = (c < 8) ? -LOG2E : 2.0f * LOG2E;
#pragma unroll
        for (int j = 0; j < 8; ++j) {
            int k = k0 + j;
            sBih[idx * 8 + j] = f2bf(k < NIN ? sc * Wih[g * NIN + k] : 0.0f);
        }
    }
    for (int idx = tid; idx < 12 * 2 * 64; idx += 256) {
        int c = idx >> 7, kk = (idx >> 6) & 1, ln = idx & 63;
        int g = 16 * c + (ln & 15), k0 = kk * 32 + (ln >> 4) * 8;
        float sc = (c < 8) ? -LOG2E : 2.0f * LOG2E;
#pragma unroll
        for (int j = 0; j < 8; ++j)
            sBhh[idx * 8 + j] = f2bf(sc * Whh[g * HID + k0 + j]);
    }
    for (int idx = tid; idx < 2 * 64; idx += 256) {
        int kk = idx >> 6, ln = idx & 63;
        int n = ln & 15, k0 = kk * 32 + (ln >> 4) * 8;
#pragma unroll
        for (int j = 0; j < 8; ++j)
            sBout[idx * 8 + j] = f2bf(n < NOUT ? Wout[n * HID + k0 + j] : 0.0f);
    }
    for (int idx = tid; idx < BM * 66 / 2; idx += 256)
        ((int*)sH)[idx] = 0;                  // h0 = 0

    const int lane = tid & 63, w = tid >> 6;
    const int q = lane >> 4, l15 = lane & 15;

    // pre-scaled per-lane biases (gate col = 16c + l15)
    float brz[8], bni[4], bnh[4];
#pragma unroll
    for (int c = 0; c < 8; ++c)
        brz[c] = -LOG2E * (bih[16 * c + l15] + bhh[16 * c + l15]);
#pragma unroll
    for (int c = 0; c < 4; ++c) {
        bni[c] = 2.0f * LOG2E * bih[128 + 16 * c + l15];
        bnh[c] = 2.0f * LOG2E * bhh[128 + 16 * c + l15];
    }
    const float bo = (l15 < NOUT) ? bout[l15] : 0.0f;

    __syncthreads();

    const int row0 = blockIdx.x * BM + 16 * w;
    int xr = row0 + l15;                      // this lane's batch row
    if (xr > BATCH - 1) xr = BATCH - 1;       // clamp (writes guarded later)
    const float* xbase = X + (long)xr * (SEQ * NIN) + q * 8;

    f4 hreg[4];                               // h in C-layout, fp32
#pragma unroll
    for (int c = 0; c < 4; ++c) hreg[c] = (f4){0.f, 0.f, 0.f, 0.f};

    // preload chunk 0 (steps 0,1): per lane 2x(float4 + float4-or-zero)
    float4 fva[2], fvb[2];
#pragma unroll
    for (int i = 0; i < 2; ++i) {
        fva[i] = *(const float4*)(xbase + i * NIN);
        fvb[i] = (q < 3) ? *(const float4*)(xbase + i * NIN + 4)
                         : make_float4(0.f, 0.f, 0.f, 0.f);
    }

#pragma unroll 1
    for (int c = 0; c < 14; ++c) {            // 14 chunks x 2 steps
        // convert prefetched chunk -> bf16 fragments (vmcnt wait lands here)
        bf8 xc[2];
#pragma unroll
        for (int i = 0; i < 2; ++i) {
            xc[i][0] = f2bf(fva[i].x); xc[i][1] = f2bf(fva[i].y);
            xc[i][2] = f2bf(fva[i].z); xc[i][3] = f2bf(fva[i].w);
            xc[i][4] = f2bf(fvb[i].x); xc[i][5] = f2bf(fvb[i].y);
            xc[i][6] = f2bf(fvb[i].z); xc[i][7] = f2bf(fvb[i].w);
        }
        // issue next chunk's loads (consumed 2 full steps later)
        if (c < 13) {
            const float* nb = xbase + (2 * c + 2) * NIN;
#pragma unroll
            for (int i = 0; i < 2; ++i) {
                fva[i] = *(const float4*)(nb + i * NIN);
                fvb[i] = (q < 3) ? *(const float4*)(nb + i * NIN + 4)
                                 : make_float4(0.f, 0.f, 0.f, 0.f);
            }
        }

#pragma unroll
        for (int ss = 0; ss < 2; ++ss) {
            const bf8 xa = xc[ss];

            // accumulators, bias-initialized
            f4 arz[8], axn[4], ahn[4];
#pragma unroll
            for (int cc = 0; cc < 8; ++cc) { f4 v = {brz[cc], brz[cc], brz[cc], brz[cc]}; arz[cc] = v; }
#pragma unroll
            for (int cc = 0; cc < 4; ++cc) {
                f4 vi = {bni[cc], bni[cc], bni[cc], bni[cc]};
                f4 vh = {bnh[cc], bnh[cc], bnh[cc], bnh[cc]};
                axn[cc] = vi; ahn[cc] = vh;
            }

            // Gh (h ready from prev step's wave-local LDS writes)
#pragma unroll
            for (int kk = 0; kk < 2; ++kk) {
                const short* p = &sH[16 * w + l15][kk * 32 + q * 8];
                bf4 lo = *(const bf4*)p;
                bf4 hi = *(const bf4*)(p + 4);
                bf8 ha;
                ha[0] = lo[0]; ha[1] = lo[1]; ha[2] = lo[2]; ha[3] = lo[3];
                ha[4] = hi[0]; ha[5] = hi[1]; ha[6] = hi[2]; ha[7] = hi[3];
#pragma unroll
                for (int cc = 0; cc < 12; ++cc) {
                    bf8 bfrag = *(const bf8*)&sBhh[((cc * 2 + kk) * 64 + lane) * 8];
                    if (cc < 8)
                        arz[cc] = __builtin_amdgcn_mfma_f32_16x16x32_bf16(ha, bfrag, arz[cc], 0, 0, 0);
                    else
                        ahn[cc - 8] = __builtin_amdgcn_mfma_f32_16x16x32_bf16(ha, bfrag, ahn[cc - 8], 0, 0, 0);
                }
            }

            // Gx
#pragma unroll
            for (int cc = 0; cc < 12; ++cc) {
                bf8 bfrag = *(const bf8*)&sBih[(cc * 64 + lane) * 8];
                if (cc < 8)
                    arz[cc] = __builtin_amdgcn_mfma_f32_16x16x32_bf16(xa, bfrag, arz[cc], 0, 0, 0);
                else
                    axn[cc - 8] = __builtin_amdgcn_mfma_f32_16x16x32_bf16(xa, bfrag, axn[cc - 8], 0, 0, 0);
            }

            // activations, all in-lane (C layout: row=4q+e, col=16hc+l15)
#pragma unroll
            for (int hc = 0; hc < 4; ++hc) {
                f4 hnew;
#pragma unroll
                for (int e = 0; e < 4; ++e) {
                    float r = __builtin_amdgcn_rcpf(1.0f + __builtin_amdgcn_exp2f(arz[hc][e]));
                    float z = __builtin_amdgcn_rcpf(1.0f + __builtin_amdgcn_exp2f(arz[hc + 4][e]));
                    float y = fmaf(r, ahn[hc][e], axn[hc][e]);
                    float t = __builtin_amdgcn_rcpf(1.0f + __builtin_amdgcn_exp2f(y));
                    float n = fmaf(-2.0f, t, 1.0f);
                    float h = fmaf(z, hreg[hc][e] - n, n);   // (1-z)*n + z*h
                    hnew[e] = h;
                    sH[16 * w + 4 * q + e][16 * hc + l15] = f2bf(h);
                }
                hreg[hc] = hnew;
            }
        }
    }

    // head: out = h @ Wout^T + bout  (one 16-col tile, K=64)
    f4 ao = {bo, bo, bo, bo};
#pragma unroll
    for (int kk = 0; kk < 2; ++kk) {
        const short* p = &sH[16 * w + l15][kk * 32 + q * 8];
        bf4 lo = *(const bf4*)p;
        bf4 hi = *(const bf4*)(p + 4);
        bf8 f;
        f[0] = lo[0]; f[1] = lo[1]; f[2] = lo[2]; f[3] = lo[3];
        f[4] = hi[0]; f[5] = hi[1]; f[6] = hi[2]; f[7] = hi[3];
        bf8 bfrag = *(const bf8*)&sBout[(kk * 64 + lane) * 8];
        ao = __builtin_amdgcn_mfma_f32_16x16x32_bf16(f, bfrag, ao, 0, 0, 0);
    }
#pragma unroll
    for (int e = 0; e < 4; ++e) {
        int r = row0 + 4 * q + e;
        if (r < BATCH && l15 < NOUT) out[r * NOUT + l15] = ao[e];
    }
}

extern "C" void kernel_launch(void* const* d_in, const int* in_sizes, int n_in,
                              void* d_out, int out_size, void* d_ws, size_t ws_size,
                              hipStream_t stream) {
    const float* X    = (const float*)d_in[0];
    const float* Wih  = (const float*)d_in[1];
    const float* Whh  = (const float*)d_in[2];
    const float* bih  = (const float*)d_in[3];
    const float* bhh  = (const float*)d_in[4];
    const float* Wout = (const float*)d_in[5];
    const float* bout = (const float*)d_in[6];
    float* out = (float*)d_out;

    gru_mfma5_kernel<<<NBLK, 256, 0, stream>>>(X, Wih, Whh, bih, bhh, Wout, bout, out);
}

// Round 4
// 601.943 us; speedup vs baseline: 2.2452x; 2.2452x over previous
//
#include <hip/hip_runtime.h>
#include <hip/hip_bf16.h>

#define BATCH 100000
#define SEQ   28
#define NIN   28
#define HID   64
#define NOUT  10
#define BM    64
#define NBLK  ((BATCH + BM - 1) / BM)
#define LOG2E 1.4426950408889634f

typedef short bf8 __attribute__((ext_vector_type(8)));   // 8 bf16 (4 VGPRs)
typedef short bf4 __attribute__((ext_vector_type(4)));
typedef float f4  __attribute__((ext_vector_type(4)));

__device__ __forceinline__ short f2bf(float f) {
    __hip_bfloat16 b = __float2bfloat16(f);   // RNE
    return *reinterpret_cast<short*>(&b);
}

// ---------------------------------------------------------------------------
// GRU v6 = v2 structure with a spill-free register budget.
// v2/v5 post-mortem: __launch_bounds__(256,2) produced a 128-VGPR budget and
// 256-1280 B/thread of scratch (WRITE_SIZE 102/514 MB vs 4 MB of output);
// v4's (256,1) binary (156 VGPR) had zero scratch. Same fix here: (256,1)
// lets the allocator take ~150-170 VGPRs. At <=170 VGPRs the HW still fits
// 3 waves/SIMD, and LDS (47.6 KB) fits 3 blocks/CU.
//
// Per block: 64 batch rows, 4 waves, wave w owns rows 16w..16w+15.
// gates[16x192] = x_t[16x32pad] @ Wih'^T + h[16x64] @ Whh'^T (+bias'); r,z
// weight rows pre-scaled by -log2e and n rows by 2*log2e so
// sigmoid(x)=rcp(1+exp2(u)) and tanh(y)=1-2*rcp(1+exp2(y')) need no in-loop
// scaling. No __syncthreads in the step loop: all data deps are wave-local.
// ---------------------------------------------------------------------------
__global__ __launch_bounds__(256, 1) void gru_mfma6_kernel(
    const float* __restrict__ X,     // [B, S, 28]
    const float* __restrict__ Wih,   // [192, 28]
    const float* __restrict__ Whh,   // [192, 64]
    const float* __restrict__ bih,   // [192]
    const float* __restrict__ bhh,   // [192]
    const float* __restrict__ Wout,  // [10, 64]
    const float* __restrict__ bout,  // [10]
    float* __restrict__ out)         // [B, 10]
{
    __shared__ short sBih[12 * 64 * 8];        // 12 KB
    __shared__ short sBhh[12 * 2 * 64 * 8];    // 24 KB
    __shared__ short sBout[2 * 64 * 8];        // 2 KB
    __shared__ short sH[BM][66];               // 8.25 KB, padded stride

    const int tid = threadIdx.x;

    // ---- one-time: fp32 weights -> pre-scaled bf16 B-fragments in LDS ----
    for (int idx = tid; idx < 12 * 64; idx += 256) {
        int c = idx >> 6, ln = idx & 63;
        int g = 16 * c + (ln & 15), k0 = (ln >> 4) * 8;
        float sc = (c < 8) ? -LOG2E : 2.0f * LOG2E;
#pragma unroll
        for (int j = 0; j < 8; ++j) {
            int k = k0 + j;
            sBih[idx * 8 + j] = f2bf(k < NIN ? sc * Wih[g * NIN + k] : 0.0f);
        }
    }
    for (int idx = tid; idx < 12 * 2 * 64; idx += 256) {
        int c = idx >> 7, kk = (idx >> 6) & 1, ln = idx & 63;
        int g = 16 * c + (ln & 15), k0 = kk * 32 + (ln >> 4) * 8;
        float sc = (c < 8) ? -LOG2E : 2.0f * LOG2E;
#pragma unroll
        for (int j = 0; j < 8; ++j)
            sBhh[idx * 8 + j] = f2bf(sc * Whh[g * HID + k0 + j]);
    }
    for (int idx = tid; idx < 2 * 64; idx += 256) {
        int kk = idx >> 6, ln = idx & 63;
        int n = ln & 15, k0 = kk * 32 + (ln >> 4) * 8;
#pragma unroll
        for (int j = 0; j < 8; ++j)
            sBout[idx * 8 + j] = f2bf(n < NOUT ? Wout[n * HID + k0 + j] : 0.0f);
    }
    for (int idx = tid; idx < BM * 66 / 2; idx += 256)
        ((int*)sH)[idx] = 0;                  // h0 = 0

    const int lane = tid & 63, w = tid >> 6;
    const int q = lane >> 4, l15 = lane & 15;

    // pre-scaled per-lane biases (gate col = 16c + l15)
    float brz[8], bni[4], bnh[4];
#pragma unroll
    for (int c = 0; c < 8; ++c)
        brz[c] = -LOG2E * (bih[16 * c + l15] + bhh[16 * c + l15]);
#pragma unroll
    for (int c = 0; c < 4; ++c) {
        bni[c] = 2.0f * LOG2E * bih[128 + 16 * c + l15];
        bnh[c] = 2.0f * LOG2E * bhh[128 + 16 * c + l15];
    }
    const float bo = (l15 < NOUT) ? bout[l15] : 0.0f;

    __syncthreads();

    const int row0 = blockIdx.x * BM + 16 * w;
    int xr = row0 + l15;                      // this lane's batch row
    if (xr > BATCH - 1) xr = BATCH - 1;       // clamp (writes guarded later)
    const float* xbase = X + (long)xr * (SEQ * NIN) + q * 8;

    f4 hreg[4];                               // h in C-layout, fp32
#pragma unroll
    for (int c = 0; c < 4; ++c) hreg[c] = (f4){0.f, 0.f, 0.f, 0.f};

    // preload x for s=0
    float4 v0n = *(const float4*)xbase;
    float4 v1n = make_float4(0.f, 0.f, 0.f, 0.f);
    if (q < 3) v1n = *(const float4*)(xbase + 4);
    bf8 xa;
    xa[0] = f2bf(v0n.x); xa[1] = f2bf(v0n.y); xa[2] = f2bf(v0n.z); xa[3] = f2bf(v0n.w);
    xa[4] = f2bf(v1n.x); xa[5] = f2bf(v1n.y); xa[6] = f2bf(v1n.z); xa[7] = f2bf(v1n.w);

#pragma unroll 1
    for (int s = 0; s < SEQ; ++s) {
        // accumulators, bias-initialized (free vs zero-init)
        f4 arz[8], axn[4], ahn[4];
#pragma unroll
        for (int c = 0; c < 8; ++c) { f4 v = {brz[c], brz[c], brz[c], brz[c]}; arz[c] = v; }
#pragma unroll
        for (int c = 0; c < 4; ++c) {
            f4 vi = {bni[c], bni[c], bni[c], bni[c]};
            f4 vh = {bnh[c], bnh[c], bnh[c], bnh[c]};
            axn[c] = vi; ahn[c] = vh;
        }

        // Gh first (h ready from prev step's wave-local LDS writes)
#pragma unroll
        for (int kk = 0; kk < 2; ++kk) {
            const short* p = &sH[16 * w + l15][kk * 32 + q * 8];
            bf4 lo = *(const bf4*)p;
            bf4 hi = *(const bf4*)(p + 4);
            bf8 ha;
            ha[0] = lo[0]; ha[1] = lo[1]; ha[2] = lo[2]; ha[3] = lo[3];
            ha[4] = hi[0]; ha[5] = hi[1]; ha[6] = hi[2]; ha[7] = hi[3];
#pragma unroll
            for (int c = 0; c < 12; ++c) {
                bf8 bfrag = *(const bf8*)&sBhh[((c * 2 + kk) * 64 + lane) * 8];
                if (c < 8)
                    arz[c] = __builtin_amdgcn_mfma_f32_16x16x32_bf16(ha, bfrag, arz[c], 0, 0, 0);
                else
                    ahn[c - 8] = __builtin_amdgcn_mfma_f32_16x16x32_bf16(ha, bfrag, ahn[c - 8], 0, 0, 0);
            }
        }

        // Gx
#pragma unroll
        for (int c = 0; c < 12; ++c) {
            bf8 bfrag = *(const bf8*)&sBih[(c * 64 + lane) * 8];
            if (c < 8)
                arz[c] = __builtin_amdgcn_mfma_f32_16x16x32_bf16(xa, bfrag, arz[c], 0, 0, 0);
            else
                axn[c - 8] = __builtin_amdgcn_mfma_f32_16x16x32_bf16(xa, bfrag, axn[c - 8], 0, 0, 0);
        }

        // prefetch x for step s+1 (latency hidden under activations)
        {
            int sn = (s < SEQ - 1) ? s + 1 : s;
            const float* p = xbase + sn * NIN;
            v0n = *(const float4*)p;
            if (q < 3) v1n = *(const float4*)(p + 4);
        }

        // activations, all in-lane (C layout: row=4q+e, col=16hc+l15)
#pragma unroll
        for (int hc = 0; hc < 4; ++hc) {
            f4 hnew;
#pragma unroll
            for (int e = 0; e < 4; ++e) {
                float r = __builtin_amdgcn_rcpf(1.0f + __builtin_amdgcn_exp2f(arz[hc][e]));
                float z = __builtin_amdgcn_rcpf(1.0f + __builtin_amdgcn_exp2f(arz[hc + 4][e]));
                float y = fmaf(r, ahn[hc][e], axn[hc][e]);
                float t = __builtin_amdgcn_rcpf(1.0f + __builtin_amdgcn_exp2f(y));
                float n = fmaf(-2.0f, t, 1.0f);
                float h = fmaf(z, hreg[hc][e] - n, n);   // (1-z)*n + z*h
                hnew[e] = h;
                sH[16 * w + 4 * q + e][16 * hc + l15] = f2bf(h);
            }
            hreg[hc] = hnew;
        }

        // convert prefetched x (vmcnt wait lands here, after activations)
        xa[0] = f2bf(v0n.x); xa[1] = f2bf(v0n.y); xa[2] = f2bf(v0n.z); xa[3] = f2bf(v0n.w);
        xa[4] = f2bf(v1n.x); xa[5] = f2bf(v1n.y); xa[6] = f2bf(v1n.z); xa[7] = f2bf(v1n.w);
    }

    // head: out = h @ Wout^T + bout  (one 16-col tile, K=64)
    f4 ao = {bo, bo, bo, bo};
#pragma unroll
    for (int kk = 0; kk < 2; ++kk) {
        const short* p = &sH[16 * w + l15][kk * 32 + q * 8];
        bf4 lo = *(const bf4*)p;
        bf4 hi = *(const bf4*)(p + 4);
        bf8 f;
        f[0] = lo[0]; f[1] = lo[1]; f[2] = lo[2]; f[3] = lo[3];
        f[4] = hi[0]; f[5] = hi[1]; f[6] = hi[2]; f[7] = hi[3];
        bf8 bfrag = *(const bf8*)&sBout[(kk * 64 + lane) * 8];
        ao = __builtin_amdgcn_mfma_f32_16x16x32_bf16(f, bfrag, ao, 0, 0, 0);
    }
#pragma unroll
    for (int e = 0; e < 4; ++e) {
        int r = row0 + 4 * q + e;
        if (r < BATCH && l15 < NOUT) out[r * NOUT + l15] = ao[e];
    }
}

extern "C" void kernel_launch(void* const* d_in, const int* in_sizes, int n_in,
                              void* d_out, int out_size, void* d_ws, size_t ws_size,
                              hipStream_t stream) {
    const float* X    = (const float*)d_in[0];
    const float* Wih  = (const float*)d_in[1];
    const float* Whh  = (const float*)d_in[2];
    const float* bih  = (const float*)d_in[3];
    const float* bhh  = (const float*)d_in[4];
    const float* Wout = (const float*)d_in[5];
    const float* bout = (const float*)d_in[6];
    float* out = (float*)d_out;

    gru_mfma6_kernel<<<NBLK, 256, 0, stream>>>(X, Wih, Whh, bih, bhh, Wout, bout, out);
}